// Round 23
// baseline (47.820 us; speedup 1.0000x reference)
//
#include <hip/hip_runtime.h>
#include <math.h>

// CasperNet R23: B=131072, D=256, H=64, O=10.
// R22's diagnostic: halving VALU work AND halving waves both left time
// unchanged -> no shared pipe binds; waves are latency-stalled. Phase-1
// x-loads are the largest un-fixed stall (register-window prefetch was
// defeated by the allocator in R7/R20: VGPR pinned 40-68). R23 uses the
// one compiler-proof mechanism: ASYNC global_load_lds double-buffering.
//  - per ks: 2 DMA instrs prefetch the next 16x128B chunk into the
//    wave's PRIVATE LDS region; s_waitcnt vmcnt(2) (counted, never 0
//    mid-loop) gates consumption. No VGPRs consumed, can't be re-sunk.
//  - conflict-free via pre-swizzled GLOBAL source (rule #21): src byte
//    offset ^= (row&7)<<4 within the row's 128B; ds_read at same-XOR
//    slot -> 2-way banks (free). LDS dest stays linear (DMA constraint).
//  - LDS 79.0KiB (sW 74 rows 37.9K + sUB 10K + xbuf 8x4K; sBias dropped,
//    bias from global L2-hot) -> 2 blocks/CU. Patches alias own xbuf.
//  - phase-1 reads sW rows 74..79 overrun into sUB: garbage bf16 only
//    reaches acc[4] cols 74..79, which are never stored. Safe.
// Math bit-identical to R19/R22 -> absmax exactly 0.03125.
// Layout (verified R5): MFMA C: col=lane&15, row=(lane>>4)*4+reg;
// A-frag: lane(lm,lg) = A[row=lm][k=lg*8+j].

#define DIMD 256
#define DIMH 64
#define DIMO 10
#define DT   320
#define NT   5        // 5 n-tiles of 16 = 80 cols (74 used)
#define TM   128      // rows per block: 8 waves x 16
#define BLOCK 512

typedef __attribute__((ext_vector_type(4))) float f32x4;
typedef __attribute__((ext_vector_type(8))) short bf16x8;

__device__ inline unsigned short f2bf(float f) {   // RNE, deterministic
    union { float f; unsigned u; } v; v.f = f;
    unsigned r = v.u + 0x7FFFu + ((v.u >> 16) & 1u);
    return (unsigned short)(r >> 16);
}
__device__ inline float sigm(float s) {
    return __builtin_amdgcn_rcpf(1.0f + __expf(-s));   // v_rcp_f32
}

__global__ __launch_bounds__(BLOCK, 2) void caspernet_kernel(
    const float* __restrict__ x,    // [B, 256]
    const float* __restrict__ Wh,   // [64, 320]
    const float* __restrict__ bh,   // [64]
    const float* __restrict__ Wo,   // [10, 320]
    const float* __restrict__ bo,   // [10]
    float* __restrict__ out,        // [B, 10]
    int B)
{
    __shared__ short sW[74 * DIMD];     // bf16 [n][k], swizzled;   37888B
    __shared__ short sUB[640 * 8];      // 10 slots x 64 lanes x 8; 10240B
    __shared__ float sX[8 * 1024];      // per-wave 2x2KB x dbuf;   32768B
                                        // total 80896B = 79.0KiB -> 2/CU

    const int tid = threadIdx.x;
    const int l  = tid & 63;
    const int w  = tid >> 6;            // wave 0..7 -> rows w*16..w*16+15
    const int lm = l & 15, lg = l >> 4;

    // DMA lane geometry: instr q covers 16 rows x 64B; lane l -> row l>>2,
    // piece l&3. Source pre-swizzled by (row&7)<<4 within the row's 128B.
    const int dr  = l >> 2, dpc = l & 3;
    const int dsw = (dr & 7) << 4;
    const size_t growbase = (size_t)blockIdx.x * TM + w * 16;
    float* xwave = sX + w * 1024;       // this wave's 4KB region

    // issue one 1KB DMA: chunk (ks,q) into buffer parity p
#define XDMA(ks, q, p)                                                        \
    {                                                                         \
        const float* gsrc = x + (growbase + dr) * 256 + (ks) * 32             \
                              + ((((q) * 64 + dpc * 16) ^ dsw) >> 2);         \
        float* ldst = xwave + (p) * 512 + (q) * 256;                          \
        __builtin_amdgcn_global_load_lds(                                     \
            (const __attribute__((address_space(1))) void*)gsrc,              \
            (__attribute__((address_space(3))) void*)ldst, 16, 0, 0);         \
    }

    // ---- prologue DMA for ks=0 (overlaps the staging barrier) ----
    XDMA(0, 0, 0)
    XDMA(0, 1, 0)

    // ---- stage W1 = [Wh_x; Wo_x] as bf16, swizzled (74 real rows) ----
    for (int idx = tid; idx < 74 * 64; idx += BLOCK) {   // 74 rows x 64 float4
        const int n = idx >> 6, k0 = (idx & 63) * 4;
        const float4 v = (n < DIMH)
            ? *reinterpret_cast<const float4*>(Wh + n * DT + k0)
            : *reinterpret_cast<const float4*>(Wo + (n - 64) * DT + k0);
        const int kz = k0 ^ ((n & 7) << 3);
        short4 sv;
        sv.x = (short)f2bf(v.x); sv.y = (short)f2bf(v.y);
        sv.z = (short)f2bf(v.z); sv.w = (short)f2bf(v.w);
        *reinterpret_cast<short4*>(sW + n * DIMD + kz) = sv;   // 8B aligned
    }
    // ---- build B-frag blob in-block ----
    for (int e = tid; e < 640; e += BLOCK) {
        const int p = e >> 6, l2 = e & 63;
        int g, t;
        if      (p < 4) { g = 0; t = p + 1; }
        else if (p < 7) { g = 1; t = p - 2; }      // p=4,5,6 -> t=2,3,4
        else if (p < 9) { g = 2; t = p - 4; }      // p=7,8   -> t=3,4
        else            { g = 3; t = 4;     }
        const int lm2 = l2 & 15, lg2 = l2 >> 4;
        const int col = t * 16 + lm2;
        short4 lo = {0, 0, 0, 0}, hi = {0, 0, 0, 0};
        if (lg2 < 2 && col < 74) {
            const float* src = (col < DIMH)
                ? (Wh + col * DT + DIMD + g * 16 + lg2 * 8)
                : (Wo + (col - DIMH) * DT + DIMD + g * 16 + lg2 * 8);
            const float4 a = *reinterpret_cast<const float4*>(src);
            const float4 b = *reinterpret_cast<const float4*>(src + 4);
            lo.x = (short)f2bf(a.x); lo.y = (short)f2bf(a.y);
            lo.z = (short)f2bf(a.z); lo.w = (short)f2bf(a.w);
            hi.x = (short)f2bf(b.x); hi.y = (short)f2bf(b.y);
            hi.z = (short)f2bf(b.z); hi.w = (short)f2bf(b.w);
        }
        *reinterpret_cast<short4*>(sUB + e * 8)     = lo;
        *reinterpret_cast<short4*>(sUB + e * 8 + 4) = hi;
    }
    __syncthreads();                    // weights visible (drains DMA0 too)

    // ---- phase 1: double-buffered DMA pipeline over 8 ks chunks ----
    f32x4 acc[NT];
    #pragma unroll
    for (int t = 0; t < NT; ++t) acc[t] = (f32x4){0.f, 0.f, 0.f, 0.f};

    #pragma unroll
    for (int ks = 0; ks < 8; ++ks) {
        if (ks < 7) {                   // prefetch next chunk, other parity
            XDMA(ks + 1, 0, (ks + 1) & 1)
            XDMA(ks + 1, 1, (ks + 1) & 1)
            asm volatile("s_waitcnt vmcnt(2)" ::: "memory");
        } else {
            asm volatile("s_waitcnt vmcnt(0)" ::: "memory");
        }
        __builtin_amdgcn_sched_barrier(0);
        // read this wave's chunk: row lm, logical bytes lg*32..+32
        const float* fb = xwave + (ks & 1) * 512;
        const int s0 = (lg * 32)      ^ ((lm & 7) << 4);   // swizzled slots
        const int s1 = (lg * 32 + 16) ^ ((lm & 7) << 4);
        const f32x4 xa = *reinterpret_cast<const f32x4*>(
            fb + ((s0 >> 6) << 8) + (lm << 4) + ((s0 & 63) >> 2));
        const f32x4 xb = *reinterpret_cast<const f32x4*>(
            fb + ((s1 >> 6) << 8) + (lm << 4) + ((s1 & 63) >> 2));
        bf16x8 af;
        af[0] = (short)f2bf(xa[0]); af[1] = (short)f2bf(xa[1]);
        af[2] = (short)f2bf(xa[2]); af[3] = (short)f2bf(xa[3]);
        af[4] = (short)f2bf(xb[0]); af[5] = (short)f2bf(xb[1]);
        af[6] = (short)f2bf(xb[2]); af[7] = (short)f2bf(xb[3]);
        #pragma unroll
        for (int t = 0; t < NT; ++t) {
            const int n = t * 16 + lm;
            const int kz = (lg * 8 + ks * 32) ^ ((n & 7) << 3);
            const bf16x8 bf = *reinterpret_cast<const bf16x8*>(sW + n * DIMD + kz);
            acc[t] = __builtin_amdgcn_mfma_f32_16x16x32_bf16(af, bf, acc[t], 0, 0, 0);
        }
    }
    // bias from global (L2-hot; same values the old sBias held)
    #pragma unroll
    for (int t = 0; t < NT; ++t) {
        const int n = t * 16 + lm;
        float bt = 0.f;
        if (n < DIMH) bt = bh[n];
        else if (n < 74) bt = bo[n - DIMH];
        acc[t][0] += bt; acc[t][1] += bt; acc[t][2] += bt; acc[t][3] += bt;
    }

    // ---- phase 2: blocked cascade; patch aliases THIS wave's xbuf ----
    float* tb = xwave;                  // 16x20 f32, private to wave w
    #pragma unroll
    for (int g = 0; g < 4; ++g) {
        // 1) transpose tile g: C(col=lm, row=lg*4+r) -> tb[row*20+col]
        #pragma unroll
        for (int r = 0; r < 4; ++r)
            tb[(lg * 4 + r) * 20 + lm] = acc[g][r];
        // lane lm picks up its ROW (4 lg copies read same addr = broadcast)
        float s[16];
        #pragma unroll
        for (int q = 0; q < 4; ++q) {
            const f32x4 v = *reinterpret_cast<const f32x4*>(tb + lm * 20 + q * 4);
            s[q * 4 + 0] = v[0]; s[q * 4 + 1] = v[1];
            s[q * 4 + 2] = v[2]; s[q * 4 + 3] = v[3];
        }
        // 2) lane-local triangular solve; coefficients via wave-uniform
        //    s_loads directly from Wh
        const float* cg = Wh + (g * 16) * DT + DIMD + g * 16;  // c(k,m)=cg[k*DT+m]
        float h[16];
        h[0] = sigm(s[0]);
        #pragma unroll
        for (int k = 1; k < 16; ++k) {
            float a_ = s[k];
            #pragma unroll
            for (int m = 0; m < k; ++m)
                a_ = fmaf(cg[k * DT + m], h[m], a_);
            h[k] = sigm(a_);
        }
        // 3) A-frag from local h (lg selects k-chunk; lg>=2 are K-pad zeros)
        bf16x8 haf;
        #pragma unroll
        for (int j = 0; j < 8; ++j) {
            const float hv = (lg == 0) ? h[j] : ((lg == 1) ? h[8 + j] : 0.f);
            haf[j] = (short)f2bf(hv);
        }
        // 4) rank-16 MFMA update of all future tiles (incl. head tile 4)
        const int pbase = (g == 0) ? 0 : (g == 1) ? 4 : (g == 2) ? 7 : 9;
        #pragma unroll
        for (int t = g + 1; t < NT; ++t) {
            const bf16x8 bf = *reinterpret_cast<const bf16x8*>(
                sUB + (pbase + t - g - 1) * 512 + l * 8);
            acc[t] = __builtin_amdgcn_mfma_f32_16x16x32_bf16(haf, bf, acc[t], 0, 0, 0);
        }
    }

    // ---- store head tile (cols 64..73 = C-tile 4) ----
    if (lm < DIMO) {
        const size_t orow0 = growbase + lg * 4;
        #pragma unroll
        for (int r = 0; r < 4; ++r)
            out[(orow0 + r) * DIMO + lm] = acc[4][r];
    }
#undef XDMA
}

extern "C" void kernel_launch(void* const* d_in, const int* in_sizes, int n_in,
                              void* d_out, int out_size, void* d_ws, size_t ws_size,
                              hipStream_t stream) {
    const float* x  = (const float*)d_in[0];
    const float* Wh = (const float*)d_in[1];
    const float* bh = (const float*)d_in[2];
    const float* Wo = (const float*)d_in[3];
    const float* bo = (const float*)d_in[4];
    float* out = (float*)d_out;

    const int B = in_sizes[0] / DIMD;      // 131072
    const int grid = B / TM;               // 1024

    hipLaunchKernelGGL(caspernet_kernel, dim3(grid), dim3(BLOCK), 0, stream,
                       x, Wh, bh, Wo, bo, out, B);
}

// Round 24
// 47.648 us; speedup vs baseline: 1.0036x; 1.0036x over previous
//
#include <hip/hip_runtime.h>
#include <math.h>

// CasperNet R24: B=131072, D=256, H=64, O=10.
// R16-R23: 8 variants pinned at 47-53us, no pipe >25%, waves ~80% stalled
// at 4 waves/SIMD. Root cause hypothesis: LDS 51-80KB (all WEIGHTS, same
// for every block) caps residency at 2 blocks/CU. R24 strips LDS to the
// per-wave patches only:
//  - prep kernel writes pre-swizzled bf16 W-blob (40KB, sW's exact
//    layout) + B-frag blob (10KB) into d_ws once per launch;
//  - main reads W/B-frags via global_load_dwordx4 from the blob (same
//    per-lane addressing as the old ds_read_b128; ~51KB working set ->
//    L1+L2 resident);
//  - LDS = 8x 16x20 f32 patches = 10.2KB -> residency VGPR-bound:
//    ~8 waves/SIMD (2x), and the kernel is BARRIER-FREE (no staging
//    prologue, no convoy).
// Math identical to R19-R23 (same bf16 values, same op order) ->
// absmax exactly 0.03125.
// Layout (verified R5): MFMA C: col=lane&15, row=(lane>>4)*4+reg;
// A-frag: lane(lm,lg) = A[row=lm][k=lg*8+j].

#define DIMD 256
#define DIMH 64
#define DIMO 10
#define DT   320
#define NT   5        // 5 n-tiles of 16 = 80 cols (74 used)
#define TM   128      // rows per block: 8 waves x 16
#define BLOCK 512
#define UBOFFS (80 * 256)   // short-offset of UB blob inside d_ws

typedef __attribute__((ext_vector_type(4))) float f32x4;
typedef __attribute__((ext_vector_type(8))) short bf16x8;

__device__ inline unsigned short f2bf(float f) {   // RNE, deterministic
    union { float f; unsigned u; } v; v.f = f;
    unsigned r = v.u + 0x7FFFu + ((v.u >> 16) & 1u);
    return (unsigned short)(r >> 16);
}
__device__ inline float sigm(float s) {
    return __builtin_amdgcn_rcpf(1.0f + __expf(-s));   // v_rcp_f32
}

// ---- prep: pre-swizzled bf16 W blob + B-frag blob into d_ws ----
__global__ void caspernet_prep(const float* __restrict__ Wh,
                               const float* __restrict__ Wo,
                               short* __restrict__ blob)
{
    const int idx = blockIdx.x * 256 + threadIdx.x;
    if (idx < 80 * 64) {                 // W blob: 80 rows x 64 float4
        const int n = idx >> 6, k0 = (idx & 63) * 4;
        float4 v = make_float4(0.f, 0.f, 0.f, 0.f);
        if (n < DIMH)      v = *reinterpret_cast<const float4*>(Wh + n * DT + k0);
        else if (n < 74)   v = *reinterpret_cast<const float4*>(Wo + (n - 64) * DT + k0);
        const int kz = k0 ^ ((n & 7) << 3);
        short* d = blob + n * DIMD + kz;
        d[0] = (short)f2bf(v.x); d[1] = (short)f2bf(v.y);
        d[2] = (short)f2bf(v.z); d[3] = (short)f2bf(v.w);
    }
    if (idx < 640) {                     // UB blob: 10 slots x 64 lanes
        const int p = idx >> 6, l2 = idx & 63;
        int g, t;
        if      (p < 4) { g = 0; t = p + 1; }
        else if (p < 7) { g = 1; t = p - 2; }      // p=4,5,6 -> t=2,3,4
        else if (p < 9) { g = 2; t = p - 4; }      // p=7,8   -> t=3,4
        else            { g = 3; t = 4;     }
        const int lm2 = l2 & 15, lg2 = l2 >> 4;
        const int col = t * 16 + lm2;
        short v[8] = {0, 0, 0, 0, 0, 0, 0, 0};
        if (lg2 < 2 && col < 74) {
            const float* src = (col < DIMH)
                ? (Wh + col * DT + DIMD + g * 16 + lg2 * 8)
                : (Wo + (col - DIMH) * DT + DIMD + g * 16 + lg2 * 8);
            for (int j = 0; j < 8; ++j) v[j] = (short)f2bf(src[j]);
        }
        short* d = blob + UBOFFS + idx * 8;
        for (int j = 0; j < 8; ++j) d[j] = v[j];
    }
}

__global__ __launch_bounds__(BLOCK, 2) void caspernet_kernel(
    const float* __restrict__ x,    // [B, 256]
    const float* __restrict__ Wh,   // [64, 320] (solve coefficients)
    const float* __restrict__ bh,   // [64]
    const float* __restrict__ bo,   // [10]
    const short* __restrict__ blob, // d_ws: W blob + UB blob (bf16)
    float* __restrict__ out,        // [B, 10]
    int B)
{
    __shared__ float sT[8 * 320];       // per-wave 16x20 patches; 10240B ONLY

    const int tid = threadIdx.x;
    const int l  = tid & 63;
    const int w  = tid >> 6;            // wave 0..7 -> rows w*16..w*16+15
    const int lm = l & 15, lg = l >> 4;

    const short* gW  = blob;            // [80][256] bf16, kz-swizzled
    const short* gUB = blob + UBOFFS;   // [640][8] bf16

    // ---- phase 1: one 16-row tile per wave; weights from L2 blob ----
    const size_t rowA = (size_t)blockIdx.x * TM + w * 16 + lm;
    const float* xr = x + rowA * DIMD + lg * 8;

    f32x4 acc[NT];
    #pragma unroll
    for (int t = 0; t < NT; ++t) acc[t] = (f32x4){0.f, 0.f, 0.f, 0.f};

    #pragma unroll
    for (int ks = 0; ks < 8; ++ks) {
        const float4 xa = *reinterpret_cast<const float4*>(xr + ks * 32);
        const float4 xb = *reinterpret_cast<const float4*>(xr + ks * 32 + 4);
        bf16x8 af;
        af[0] = (short)f2bf(xa.x); af[1] = (short)f2bf(xa.y);
        af[2] = (short)f2bf(xa.z); af[3] = (short)f2bf(xa.w);
        af[4] = (short)f2bf(xb.x); af[5] = (short)f2bf(xb.y);
        af[6] = (short)f2bf(xb.z); af[7] = (short)f2bf(xb.w);
        #pragma unroll
        for (int t = 0; t < NT; ++t) {
            const int n = t * 16 + lm;
            const int kz = (lg * 8 + ks * 32) ^ ((n & 7) << 3);
            const bf16x8 bf = *reinterpret_cast<const bf16x8*>(gW + n * DIMD + kz);
            acc[t] = __builtin_amdgcn_mfma_f32_16x16x32_bf16(af, bf, acc[t], 0, 0, 0);
        }
    }
    // bias from global (L2-hot)
    #pragma unroll
    for (int t = 0; t < NT; ++t) {
        const int n = t * 16 + lm;
        float bt = 0.f;
        if (n < DIMH) bt = bh[n];
        else if (n < 74) bt = bo[n - DIMH];
        acc[t][0] += bt; acc[t][1] += bt; acc[t][2] += bt; acc[t][3] += bt;
    }

    // ---- phase 2: blocked cascade; patch is wave-private (no barriers) ----
    float* tb = sT + w * 320;           // 16x20 f32, private to wave w
    #pragma unroll
    for (int g = 0; g < 4; ++g) {
        // 1) transpose tile g: C(col=lm, row=lg*4+r) -> tb[row*20+col]
        #pragma unroll
        for (int r = 0; r < 4; ++r)
            tb[(lg * 4 + r) * 20 + lm] = acc[g][r];
        // lane lm picks up its ROW (4 lg copies read same addr = broadcast)
        float s[16];
        #pragma unroll
        for (int q = 0; q < 4; ++q) {
            const f32x4 v = *reinterpret_cast<const f32x4*>(tb + lm * 20 + q * 4);
            s[q * 4 + 0] = v[0]; s[q * 4 + 1] = v[1];
            s[q * 4 + 2] = v[2]; s[q * 4 + 3] = v[3];
        }
        // 2) lane-local triangular solve; coefficients via wave-uniform
        //    s_loads directly from Wh
        const float* cg = Wh + (g * 16) * DT + DIMD + g * 16;  // c(k,m)=cg[k*DT+m]
        float h[16];
        h[0] = sigm(s[0]);
        #pragma unroll
        for (int k = 1; k < 16; ++k) {
            float a_ = s[k];
            #pragma unroll
            for (int m = 0; m < k; ++m)
                a_ = fmaf(cg[k * DT + m], h[m], a_);
            h[k] = sigm(a_);
        }
        // 3) A-frag from local h (lg selects k-chunk; lg>=2 are K-pad zeros)
        bf16x8 haf;
        #pragma unroll
        for (int j = 0; j < 8; ++j) {
            const float hv = (lg == 0) ? h[j] : ((lg == 1) ? h[8 + j] : 0.f);
            haf[j] = (short)f2bf(hv);
        }
        // 4) rank-16 MFMA update of all future tiles (incl. head tile 4)
        const int pbase = (g == 0) ? 0 : (g == 1) ? 4 : (g == 2) ? 7 : 9;
        #pragma unroll
        for (int t = g + 1; t < NT; ++t) {
            const bf16x8 bf = *reinterpret_cast<const bf16x8*>(
                gUB + (pbase + t - g - 1) * 512 + l * 8);
            acc[t] = __builtin_amdgcn_mfma_f32_16x16x32_bf16(haf, bf, acc[t], 0, 0, 0);
        }
    }

    // ---- store head tile (cols 64..73 = C-tile 4) ----
    if (lm < DIMO) {
        const size_t orow0 = (size_t)blockIdx.x * TM + w * 16 + lg * 4;
        #pragma unroll
        for (int r = 0; r < 4; ++r)
            out[(orow0 + r) * DIMO + lm] = acc[4][r];
    }
}

extern "C" void kernel_launch(void* const* d_in, const int* in_sizes, int n_in,
                              void* d_out, int out_size, void* d_ws, size_t ws_size,
                              hipStream_t stream) {
    const float* x  = (const float*)d_in[0];
    const float* Wh = (const float*)d_in[1];
    const float* bh = (const float*)d_in[2];
    const float* Wo = (const float*)d_in[3];
    const float* bo = (const float*)d_in[4];
    float* out = (float*)d_out;
    short* blob = (short*)d_ws;            // 40960B W + 10240B UB = 51200B

    const int B = in_sizes[0] / DIMD;      // 131072

    hipLaunchKernelGGL(caspernet_prep, dim3(20), dim3(256), 0, stream,
                       Wh, Wo, blob);

    const int grid = B / TM;               // 1024
    hipLaunchKernelGGL(caspernet_kernel, dim3(grid), dim3(BLOCK), 0, stream,
                       x, Wh, bh, bo, blob, out, B);
}